// Round 9
// baseline (277.843 us; speedup 1.0000x reference)
//
#include <hip/hip_runtime.h>
#include <hip/hip_bf16.h>

#define N_NODES 50000
#define N_EDGES 800000
#define HID 128

using short8  = __attribute__((ext_vector_type(8))) short;
using floatx4 = __attribute__((ext_vector_type(4))) float;

__device__ __forceinline__ float bf2f(ushort u) {
    union { uint u32; float f; } v; v.u32 = ((uint)u) << 16; return v.f;
}
__device__ __forceinline__ ushort f2bf(float f) {
    __hip_bfloat16 b = __float2bfloat16(f);
    return *reinterpret_cast<ushort*>(&b);
}

// ---- fused prep: weight transpose/bf16 + tailpack + zero(counts,cursor) ----
__global__ __launch_bounds__(256) void prep_kernel(
    const float* __restrict__ mw1, const float* __restrict__ mb1,
    const float* __restrict__ mw2,
    const float* __restrict__ uw1, const float* __restrict__ uw2,
    ushort* __restrict__ w1at, ushort* __restrict__ w1bt,
    ushort* __restrict__ w2t,
    ushort* __restrict__ uw1t, ushort* __restrict__ uw2t,
    float4* __restrict__ tailpack,
    float4* __restrict__ counts4, float4* __restrict__ cursor4)
{
    int gid = blockIdx.x * 256 + threadIdx.x;
    if (gid < 16384) {
        int c = gid >> 7, k = gid & 127;
        w1at[c * 128 + k] = f2bf(mw1[(size_t)k * HID + c]);
    } else if (gid < 32768) {
        int g = gid - 16384, c = g >> 7, k = g & 127;
        w1bt[c * 128 + k] = f2bf(mw1[(size_t)(128 + k) * HID + c]);
    } else if (gid < 49152) {
        int g = gid - 32768, c = g >> 7, k = g & 127;
        w2t[c * 128 + k] = f2bf(mw2[(size_t)k * HID + c]);
    } else if (gid < 81920) {
        int g = gid - 49152, c = g >> 8, k = g & 255;
        uw1t[c * 256 + k] = f2bf(uw1[(size_t)k * HID + c]);
    } else if (gid < 98304) {
        int g = gid - 81920, c = g >> 7, k = g & 127;
        uw2t[c * 128 + k] = f2bf(uw2[(size_t)k * HID + c]);
    } else if (gid < 98432) {
        int c = gid - 98304;
        tailpack[c] = make_float4(mw1[(size_t)256 * HID + c],
                                  mw1[(size_t)257 * HID + c],
                                  mw1[(size_t)258 * HID + c],
                                  mb1[c]);
    } else if (gid < 110936) {
        counts4[gid - 98432] = make_float4(0.f, 0.f, 0.f, 0.f);
    } else if (gid < 123440) {
        cursor4[gid - 110936] = make_float4(0.f, 0.f, 0.f, 0.f);
    }
}

// ---------------- CSR build ----------------
__global__ __launch_bounds__(256) void hist_kernel(
    const int* __restrict__ ei, uint* __restrict__ counts)
{
    int e = blockIdx.x * 256 + threadIdx.x;
    if (e < N_EDGES) atomicAdd(&counts[ei[N_EDGES + e]], 1u);
}

#define SCAN_B 196
__global__ __launch_bounds__(256) void scan1_kernel(
    const uint* __restrict__ counts, uint* __restrict__ partials)
{
    __shared__ uint sm[256];
    int b = blockIdx.x, tid = threadIdx.x;
    int i = b * 256 + tid;
    sm[tid] = (i < N_NODES) ? counts[i] : 0u;
    __syncthreads();
    for (int off = 128; off > 0; off >>= 1) {
        if (tid < off) sm[tid] += sm[tid + off];
        __syncthreads();
    }
    if (tid == 0) partials[b] = sm[0];
}

__global__ __launch_bounds__(256) void scan2_kernel(uint* __restrict__ partials)
{
    __shared__ uint sm[256];
    int tid = threadIdx.x;
    uint v = (tid < SCAN_B) ? partials[tid] : 0u;
    sm[tid] = v;
    __syncthreads();
    for (int off = 1; off < 256; off <<= 1) {
        uint t = (tid >= off) ? sm[tid - off] : 0u;
        __syncthreads();
        sm[tid] += t;
        __syncthreads();
    }
    if (tid < SCAN_B) partials[tid] = sm[tid] - v;   // exclusive
}

__global__ __launch_bounds__(256) void scan3_kernel(
    const uint* __restrict__ counts, const uint* __restrict__ partials,
    uint* __restrict__ rowptr)
{
    __shared__ uint sm[256];
    int b = blockIdx.x, tid = threadIdx.x;
    int i = b * 256 + tid;
    uint v = (i < N_NODES) ? counts[i] : 0u;
    sm[tid] = v;
    __syncthreads();
    for (int off = 1; off < 256; off <<= 1) {
        uint t = (tid >= off) ? sm[tid - off] : 0u;
        __syncthreads();
        sm[tid] += t;
        __syncthreads();
    }
    if (i < N_NODES) rowptr[i] = sm[tid] - v + partials[b];
    if (i == N_NODES - 1) rowptr[N_NODES] = N_EDGES;
}

// ---- build: scatter packed payload {src,-,ea01,ea2} to dst-sorted position --
__global__ __launch_bounds__(256) void build_kernel(
    const int* __restrict__ ei, const float* __restrict__ ea,
    const uint* __restrict__ rowptr, uint* __restrict__ cursor,
    uint4* __restrict__ epack)
{
    int e = blockIdx.x * 256 + threadIdx.x;
    if (e >= N_EDGES) return;
    int src = ei[e];
    int dst = ei[N_EDGES + e];
    uint pos = rowptr[dst] + atomicAdd(&cursor[dst], 1u);
    uint4 p;
    p.x = (uint)src;
    p.y = 0u;
    p.z = (uint)f2bf(ea[(size_t)e * 3 + 0]) | ((uint)f2bf(ea[(size_t)e * 3 + 1]) << 16);
    p.w = (uint)f2bf(ea[(size_t)e * 3 + 2]);
    epack[pos] = p;
}

// ---------------- pre: h = x@enc_w+enc_b (bf16); A = h@W1a; B = h@W1b ----------
__global__ __launch_bounds__(512, 2) void pre_kernel(
    const float* __restrict__ x, const float* __restrict__ enc_w,
    const float* __restrict__ enc_b,
    const ushort* __restrict__ w1at, const ushort* __restrict__ w1bt,
    ushort* __restrict__ hb, ushort* __restrict__ Abuf, ushort* __restrict__ Bbuf)
{
    __shared__ __align__(16) ushort htile[64][152];
    __shared__ __align__(16) ushort ABst[64][280];
    __shared__ float x_s[64][6];
    __shared__ float encw_s[640];
    __shared__ float encb_s[128];

    int tid = threadIdx.x;
    int n0 = blockIdx.x * 64;

    if (tid < 320) {
        int nl = tid / 5, k = tid % 5;
        int n = n0 + nl;
        x_s[nl][k] = (n < N_NODES) ? x[(size_t)n * 5 + k] : 0.f;
    }
    if (tid < 128) encb_s[tid] = enc_b[tid];
    encw_s[tid] = enc_w[tid];
    if (tid < 128) encw_s[512 + tid] = enc_w[512 + tid];
    __syncthreads();

    {
        int el = tid >> 3, q = tid & 7;
        int c0 = q * 16;
        union { ushort u[16]; uint4 v[2]; } hv;
#pragma unroll
        for (int c = 0; c < 16; ++c) {
            int j = c0 + c;
            float acc = encb_s[j];
#pragma unroll
            for (int k = 0; k < 5; ++k)
                acc = fmaf(x_s[el][k], encw_s[k * 128 + j], acc);
            hv.u[c] = f2bf(acc);
        }
        *(uint4*)&htile[el][c0]     = hv.v[0];
        *(uint4*)&htile[el][c0 + 8] = hv.v[1];
        int n = n0 + el;
        if (n < N_NODES) {
            uint4* gp = (uint4*)(hb + (size_t)n * HID + c0);
            gp[0] = hv.v[0];
            gp[1] = hv.v[1];
        }
    }
    __syncthreads();

    int lane = tid & 63;
    int wid  = tid >> 6;
    int cg   = wid & 3;
    int mg   = wid >> 2;
    int lhi  = lane >> 4;
    int llo  = lane & 15;
    int col0 = cg * 32 + llo;
    int col1 = cg * 32 + 16 + llo;

    {
        floatx4 acc[2][2];
#pragma unroll
        for (int lm = 0; lm < 2; ++lm)
#pragma unroll
            for (int r = 0; r < 4; ++r) { acc[lm][0][r] = 0.f; acc[lm][1][r] = 0.f; }
        const ushort* bp0 = w1at + (size_t)col0 * 128 + lhi * 8;
        const ushort* bp1 = w1at + (size_t)col1 * 128 + lhi * 8;
#pragma unroll
        for (int kk = 0; kk < 4; ++kk) {
            short8 bf0 = *(const short8*)(bp0 + kk * 32);
            short8 bf1 = *(const short8*)(bp1 + kk * 32);
#pragma unroll
            for (int lm = 0; lm < 2; ++lm) {
                int row = (mg * 2 + lm) * 16 + llo;
                short8 a = *(const short8*)((const char*)htile + (size_t)row * 304 + kk * 64 + lhi * 16);
                acc[lm][0] = __builtin_amdgcn_mfma_f32_16x16x32_bf16(a, bf0, acc[lm][0], 0, 0, 0);
                acc[lm][1] = __builtin_amdgcn_mfma_f32_16x16x32_bf16(a, bf1, acc[lm][1], 0, 0, 0);
            }
        }
#pragma unroll
        for (int lm = 0; lm < 2; ++lm)
#pragma unroll
            for (int r = 0; r < 4; ++r) {
                int row = (mg * 2 + lm) * 16 + lhi * 4 + r;
                ABst[row][col0] = f2bf(acc[lm][0][r]);
                ABst[row][col1] = f2bf(acc[lm][1][r]);
            }
    }
    {
        floatx4 acc[2][2];
#pragma unroll
        for (int lm = 0; lm < 2; ++lm)
#pragma unroll
            for (int r = 0; r < 4; ++r) { acc[lm][0][r] = 0.f; acc[lm][1][r] = 0.f; }
        const ushort* bp0 = w1bt + (size_t)col0 * 128 + lhi * 8;
        const ushort* bp1 = w1bt + (size_t)col1 * 128 + lhi * 8;
#pragma unroll
        for (int kk = 0; kk < 4; ++kk) {
            short8 bf0 = *(const short8*)(bp0 + kk * 32);
            short8 bf1 = *(const short8*)(bp1 + kk * 32);
#pragma unroll
            for (int lm = 0; lm < 2; ++lm) {
                int row = (mg * 2 + lm) * 16 + llo;
                short8 a = *(const short8*)((const char*)htile + (size_t)row * 304 + kk * 64 + lhi * 16);
                acc[lm][0] = __builtin_amdgcn_mfma_f32_16x16x32_bf16(a, bf0, acc[lm][0], 0, 0, 0);
                acc[lm][1] = __builtin_amdgcn_mfma_f32_16x16x32_bf16(a, bf1, acc[lm][1], 0, 0, 0);
            }
        }
#pragma unroll
        for (int lm = 0; lm < 2; ++lm)
#pragma unroll
            for (int r = 0; r < 4; ++r) {
                int row = (mg * 2 + lm) * 16 + lhi * 4 + r;
                ABst[row][128 + col0] = f2bf(acc[lm][0][r]);
                ABst[row][128 + col1] = f2bf(acc[lm][1][r]);
            }
    }
    __syncthreads();

    {
        int el = tid >> 3, q = tid & 7;
        int n = n0 + el;
        if (n < N_NODES) {
            uint4* ga = (uint4*)(Abuf + (size_t)n * HID + q * 16);
            ga[0] = *(uint4*)&ABst[el][q * 16];
            ga[1] = *(uint4*)&ABst[el][q * 16 + 8];
            uint4* gb = (uint4*)(Bbuf + (size_t)n * HID + q * 16);
            gb[0] = *(uint4*)&ABst[el][128 + q * 16];
            gb[1] = *(uint4*)&ABst[el][128 + q * 16 + 8];
        }
    }
}

// ---- fused upd: per-node CSR edge aggregation (regs) -> Tt tile ->
//      aggr = Tt@W2 + deg*b2 -> node MLP -> residual -> decode ----------------
__global__ __launch_bounds__(512, 2) void upd_kernel(
    const ushort* __restrict__ hb,
    const ushort* __restrict__ Abuf, const ushort* __restrict__ Bbuf,
    const uint4* __restrict__ epack, const float4* __restrict__ tailpack,
    const uint* __restrict__ rowptr,
    const ushort* __restrict__ w2t, const float* __restrict__ mb2,
    const float* __restrict__ ub1, const float* __restrict__ ub2,
    const ushort* __restrict__ uw1t, const ushort* __restrict__ uw2t,
    const float* __restrict__ dec_w, const float* __restrict__ dec_b,
    float* __restrict__ out)
{
    __shared__ __align__(16) ushort comb[64][280];   // [h | aggr], pitch 560B
    __shared__ __align__(16) ushort Tt[64][152];     // t1-sum bf16 / later hf
    __shared__ __align__(16) ushort t1s[64][152];
    __shared__ float deg_s[64];

    int tid = threadIdx.x;
    int n0 = blockIdx.x * 64;
    int lane = tid & 63;
    int wv   = tid >> 6;

    // ---- issue h loads into regs (latency hidden under edge phase) ----
    int el = tid >> 3, q = tid & 7;
    int nh = n0 + el;
    uint4 hv0 = make_uint4(0, 0, 0, 0), hv1 = make_uint4(0, 0, 0, 0);
    if (nh < N_NODES) {
        const uint4* gp = (const uint4*)(hb + (size_t)nh * HID + q * 16);
        hv0 = gp[0];
        hv1 = gp[1];
    }
    if (tid < 64) {
        int n2 = n0 + tid;
        deg_s[tid] = (n2 < N_NODES) ? (float)(rowptr[n2 + 1] - rowptr[n2]) : 0.f;
    }

    // ---- edge phase: wave wv handles nodes n0+wv*8 .. +7; cols {2*lane,2*lane+1}
    {
        float4 tp0 = tailpack[2 * lane];
        float4 tp1 = tailpack[2 * lane + 1];
#pragma unroll
        for (int i = 0; i < 8; ++i) {
            int nl = wv * 8 + i;
            int n = n0 + nl;
            float acc0 = 0.f, acc1 = 0.f, acc0b = 0.f, acc1b = 0.f;
            if (n < N_NODES) {
                uint start = rowptr[n], end = rowptr[n + 1];
                uint au = ((const uint*)(Abuf + (size_t)n * HID))[lane];
                float a0 = bf2f((ushort)(au & 0xffffu));
                float a1 = bf2f((ushort)(au >> 16));
                uint j = start;
                for (; j + 2 <= end; j += 2) {
                    uint4 pa = epack[j];
                    uint4 pb = epack[j + 1];
                    uint bua = ((const uint*)(Bbuf + (size_t)pa.x * HID))[lane];
                    uint bub = ((const uint*)(Bbuf + (size_t)pb.x * HID))[lane];
                    float e0a = bf2f((ushort)(pa.z & 0xffffu));
                    float e1a = bf2f((ushort)(pa.z >> 16));
                    float e2a = bf2f((ushort)(pa.w & 0xffffu));
                    float t0 = fmaf(e0a, tp0.x, fmaf(e1a, tp0.y, fmaf(e2a, tp0.z, tp0.w)))
                               + a0 + bf2f((ushort)(bua & 0xffffu));
                    float t1 = fmaf(e0a, tp1.x, fmaf(e1a, tp1.y, fmaf(e2a, tp1.z, tp1.w)))
                               + a1 + bf2f((ushort)(bua >> 16));
                    acc0 += fmaxf(t0, 0.f);
                    acc1 += fmaxf(t1, 0.f);
                    float e0b = bf2f((ushort)(pb.z & 0xffffu));
                    float e1b = bf2f((ushort)(pb.z >> 16));
                    float e2b = bf2f((ushort)(pb.w & 0xffffu));
                    float t0b = fmaf(e0b, tp0.x, fmaf(e1b, tp0.y, fmaf(e2b, tp0.z, tp0.w)))
                                + a0 + bf2f((ushort)(bub & 0xffffu));
                    float t1b = fmaf(e0b, tp1.x, fmaf(e1b, tp1.y, fmaf(e2b, tp1.z, tp1.w)))
                                + a1 + bf2f((ushort)(bub >> 16));
                    acc0b += fmaxf(t0b, 0.f);
                    acc1b += fmaxf(t1b, 0.f);
                }
                if (j < end) {
                    uint4 pa = epack[j];
                    uint bua = ((const uint*)(Bbuf + (size_t)pa.x * HID))[lane];
                    float e0a = bf2f((ushort)(pa.z & 0xffffu));
                    float e1a = bf2f((ushort)(pa.z >> 16));
                    float e2a = bf2f((ushort)(pa.w & 0xffffu));
                    float t0 = fmaf(e0a, tp0.x, fmaf(e1a, tp0.y, fmaf(e2a, tp0.z, tp0.w)))
                               + a0 + bf2f((ushort)(bua & 0xffffu));
                    float t1 = fmaf(e0a, tp1.x, fmaf(e1a, tp1.y, fmaf(e2a, tp1.z, tp1.w)))
                               + a1 + bf2f((ushort)(bua >> 16));
                    acc0 += fmaxf(t0, 0.f);
                    acc1 += fmaxf(t1, 0.f);
                }
                acc0 += acc0b;
                acc1 += acc1b;
            }
            uint packed = (uint)f2bf(acc0) | ((uint)f2bf(acc1) << 16);
            *(uint*)((char*)Tt + (size_t)nl * 304 + (size_t)lane * 4) = packed;
        }
    }

    // ---- commit h tile ----
    *(uint4*)&comb[el][q * 16]     = hv0;
    *(uint4*)&comb[el][q * 16 + 8] = hv1;
    __syncthreads();

    int wid  = wv;
    int cg   = wid & 3;
    int mg   = wid >> 2;
    int lhi  = lane >> 4;
    int llo  = lane & 15;
    int col0 = cg * 32 + llo;
    int col1 = cg * 32 + 16 + llo;

    // ---- aggr = Tt @ W2 + deg*b2 -> comb[.,128:256] ----
    {
        floatx4 acc[2][2];
        float b0 = mb2[col0], b1 = mb2[col1];
#pragma unroll
        for (int lm = 0; lm < 2; ++lm)
#pragma unroll
            for (int r = 0; r < 4; ++r) {
                int row = (mg * 2 + lm) * 16 + lhi * 4 + r;
                acc[lm][0][r] = deg_s[row] * b0;
                acc[lm][1][r] = deg_s[row] * b1;
            }
        const ushort* bp0 = w2t + (size_t)col0 * 128 + lhi * 8;
        const ushort* bp1 = w2t + (size_t)col1 * 128 + lhi * 8;
#pragma unroll
        for (int kk = 0; kk < 4; ++kk) {
            short8 bf0 = *(const short8*)(bp0 + kk * 32);
            short8 bf1 = *(const short8*)(bp1 + kk * 32);
#pragma unroll
            for (int lm = 0; lm < 2; ++lm) {
                int row = (mg * 2 + lm) * 16 + llo;
                short8 a = *(const short8*)((const char*)Tt + (size_t)row * 304 + kk * 64 + lhi * 16);
                acc[lm][0] = __builtin_amdgcn_mfma_f32_16x16x32_bf16(a, bf0, acc[lm][0], 0, 0, 0);
                acc[lm][1] = __builtin_amdgcn_mfma_f32_16x16x32_bf16(a, bf1, acc[lm][1], 0, 0, 0);
            }
        }
#pragma unroll
        for (int lm = 0; lm < 2; ++lm)
#pragma unroll
            for (int r = 0; r < 4; ++r) {
                int row = (mg * 2 + lm) * 16 + lhi * 4 + r;
                comb[row][128 + col0] = f2bf(acc[lm][0][r]);
                comb[row][128 + col1] = f2bf(acc[lm][1][r]);
            }
    }
    __syncthreads();

    // ---- layer 1: comb @ uw1 + ub1, relu ----
    {
        floatx4 acc[2][2];
        float b0 = ub1[col0], b1 = ub1[col1];
#pragma unroll
        for (int lm = 0; lm < 2; ++lm)
#pragma unroll
            for (int r = 0; r < 4; ++r) { acc[lm][0][r] = b0; acc[lm][1][r] = b1; }
        const ushort* bp0 = uw1t + (size_t)col0 * 256 + lhi * 8;
        const ushort* bp1 = uw1t + (size_t)col1 * 256 + lhi * 8;
#pragma unroll
        for (int kk = 0; kk < 8; ++kk) {
            short8 bf0 = *(const short8*)(bp0 + kk * 32);
            short8 bf1 = *(const short8*)(bp1 + kk * 32);
#pragma unroll
            for (int lm = 0; lm < 2; ++lm) {
                int row = (mg * 2 + lm) * 16 + llo;
                short8 a = *(const short8*)((const char*)comb + (size_t)row * 560 + kk * 64 + lhi * 16);
                acc[lm][0] = __builtin_amdgcn_mfma_f32_16x16x32_bf16(a, bf0, acc[lm][0], 0, 0, 0);
                acc[lm][1] = __builtin_amdgcn_mfma_f32_16x16x32_bf16(a, bf1, acc[lm][1], 0, 0, 0);
            }
        }
#pragma unroll
        for (int lm = 0; lm < 2; ++lm)
#pragma unroll
            for (int r = 0; r < 4; ++r) {
                int row = (mg * 2 + lm) * 16 + lhi * 4 + r;
                t1s[row][col0] = f2bf(fmaxf(acc[lm][0][r], 0.f));
                t1s[row][col1] = f2bf(fmaxf(acc[lm][1][r], 0.f));
            }
    }
    __syncthreads();

    // ---- layer 2 + residual -> Tt (hf) ----
    {
        floatx4 acc[2][2];
        float b0 = ub2[col0], b1 = ub2[col1];
#pragma unroll
        for (int lm = 0; lm < 2; ++lm)
#pragma unroll
            for (int r = 0; r < 4; ++r) { acc[lm][0][r] = b0; acc[lm][1][r] = b1; }
        const ushort* bp0 = uw2t + (size_t)col0 * 128 + lhi * 8;
        const ushort* bp1 = uw2t + (size_t)col1 * 128 + lhi * 8;
#pragma unroll
        for (int kk = 0; kk < 4; ++kk) {
            short8 bf0 = *(const short8*)(bp0 + kk * 32);
            short8 bf1 = *(const short8*)(bp1 + kk * 32);
#pragma unroll
            for (int lm = 0; lm < 2; ++lm) {
                int row = (mg * 2 + lm) * 16 + llo;
                short8 a = *(const short8*)((const char*)t1s + (size_t)row * 304 + kk * 64 + lhi * 16);
                acc[lm][0] = __builtin_amdgcn_mfma_f32_16x16x32_bf16(a, bf0, acc[lm][0], 0, 0, 0);
                acc[lm][1] = __builtin_amdgcn_mfma_f32_16x16x32_bf16(a, bf1, acc[lm][1], 0, 0, 0);
            }
        }
        __syncthreads();   // Tt reads (aggr GEMM) done; safe to overwrite
#pragma unroll
        for (int lm = 0; lm < 2; ++lm)
#pragma unroll
            for (int r = 0; r < 4; ++r) {
                int row = (mg * 2 + lm) * 16 + lhi * 4 + r;
                float h0 = bf2f(comb[row][col0]);
                float h1 = bf2f(comb[row][col1]);
                Tt[row][col0] = f2bf(h0 + acc[lm][0][r]);
                Tt[row][col1] = f2bf(h1 + acc[lm][1][r]);
            }
    }
    __syncthreads();

    // ---- decode ----
    if (tid < 320) {
        int nl = tid / 5;
        int c = tid % 5;
        int n = n0 + nl;
        if (n < N_NODES) {
            float acc0 = dec_b[c];
            for (int j = 0; j < HID; ++j)
                acc0 = fmaf(bf2f(Tt[nl][j]), dec_w[(size_t)j * 5 + c], acc0);
            out[(size_t)n * 5 + c] = acc0;
        }
    }
}

extern "C" void kernel_launch(void* const* d_in, const int* in_sizes, int n_in,
                              void* d_out, int out_size, void* d_ws, size_t ws_size,
                              hipStream_t stream) {
    const float* x     = (const float*)d_in[0];
    const int*   ei    = (const int*)d_in[1];
    const float* ea    = (const float*)d_in[2];
    const float* enc_w = (const float*)d_in[3];
    const float* enc_b = (const float*)d_in[4];
    const float* dec_w = (const float*)d_in[5];
    const float* dec_b = (const float*)d_in[6];
    // Only layer l=3 contributes (loop overwrites h_update; h never changes).
    const float* mw1 = (const float*)d_in[7]  + (size_t)3 * 259 * HID;
    const float* mb1 = (const float*)d_in[8]  + (size_t)3 * HID;
    const float* mw2 = (const float*)d_in[9]  + (size_t)3 * HID * HID;
    const float* mb2 = (const float*)d_in[10] + (size_t)3 * HID;
    const float* uw1 = (const float*)d_in[11] + (size_t)3 * 256 * HID;
    const float* ub1 = (const float*)d_in[12] + (size_t)3 * HID;
    const float* uw2 = (const float*)d_in[13] + (size_t)3 * HID * HID;
    const float* ub2 = (const float*)d_in[14] + (size_t)3 * HID;

    char* w = (char*)d_ws;
    ushort* hb     = (ushort*)w;  w += (size_t)N_NODES * HID * 2;   // 12.8MB
    ushort* Abuf   = (ushort*)w;  w += (size_t)N_NODES * HID * 2;   // 12.8MB
    ushort* Bbuf   = (ushort*)w;  w += (size_t)N_NODES * HID * 2;   // 12.8MB
    uint*   counts = (uint*)w;    w += (size_t)50016 * 4;
    uint*   cursor = (uint*)w;    w += (size_t)50016 * 4;
    uint*   rowptr = (uint*)w;    w += (size_t)50016 * 4;
    uint*   partials=(uint*)w;    w += (size_t)256 * 4;
    uint4*  epack  = (uint4*)w;   w += (size_t)N_EDGES * 16;        // 12.8MB
    ushort* w1at   = (ushort*)w;  w += (size_t)128 * 128 * 2;
    ushort* w1bt   = (ushort*)w;  w += (size_t)128 * 128 * 2;
    ushort* w2t    = (ushort*)w;  w += (size_t)128 * 128 * 2;
    ushort* uw1t   = (ushort*)w;  w += (size_t)128 * 256 * 2;
    ushort* uw2t   = (ushort*)w;  w += (size_t)128 * 128 * 2;
    float4* tailpack = (float4*)w; w += (size_t)128 * 16;
    float*  out    = (float*)d_out;

    prep_kernel<<<(123440 + 255) / 256, 256, 0, stream>>>(
        mw1, mb1, mw2, uw1, uw2, w1at, w1bt, w2t, uw1t, uw2t, tailpack,
        (float4*)counts, (float4*)cursor);
    hist_kernel<<<(N_EDGES + 255) / 256, 256, 0, stream>>>(ei, counts);
    scan1_kernel<<<SCAN_B, 256, 0, stream>>>(counts, partials);
    scan2_kernel<<<1, 256, 0, stream>>>(partials);
    scan3_kernel<<<SCAN_B, 256, 0, stream>>>(counts, partials, rowptr);
    build_kernel<<<(N_EDGES + 255) / 256, 256, 0, stream>>>(ei, ea, rowptr, cursor, epack);
    pre_kernel<<<(N_NODES + 63) / 64, 512, 0, stream>>>(
        x, enc_w, enc_b, w1at, w1bt, hb, Abuf, Bbuf);
    upd_kernel<<<(N_NODES + 63) / 64, 512, 0, stream>>>(
        hb, Abuf, Bbuf, epack, tailpack, rowptr,
        w2t, mb2, ub1, ub2, uw1t, uw2t, dec_w, dec_b, out);
}

// Round 10
// 248.000 us; speedup vs baseline: 1.1203x; 1.1203x over previous
//
#include <hip/hip_runtime.h>
#include <hip/hip_bf16.h>

#define N_NODES 50000
#define N_EDGES 800000
#define HID 128

using short8  = __attribute__((ext_vector_type(8))) short;
using floatx4 = __attribute__((ext_vector_type(4))) float;

__device__ __forceinline__ float bf2f(ushort u) {
    union { uint u32; float f; } v; v.u32 = ((uint)u) << 16; return v.f;
}
__device__ __forceinline__ ushort f2bf(float f) {
    __hip_bfloat16 b = __float2bfloat16(f);
    return *reinterpret_cast<ushort*>(&b);
}

// ---- fused prep: weight transpose/bf16 + tailpack + zero(counts,cursor,T) ----
__global__ __launch_bounds__(256) void prep_kernel(
    const float* __restrict__ mw1, const float* __restrict__ mb1,
    const float* __restrict__ mw2,
    const float* __restrict__ uw1, const float* __restrict__ uw2,
    ushort* __restrict__ w1at, ushort* __restrict__ w1bt,
    ushort* __restrict__ w2t,
    ushort* __restrict__ uw1t, ushort* __restrict__ uw2t,
    float4* __restrict__ tailpack,
    float4* __restrict__ counts4, float4* __restrict__ cursor4,
    float4* __restrict__ T4)
{
    int gid = blockIdx.x * 256 + threadIdx.x;
    if (gid < 16384) {
        int c = gid >> 7, k = gid & 127;
        w1at[c * 128 + k] = f2bf(mw1[(size_t)k * HID + c]);
    } else if (gid < 32768) {
        int g = gid - 16384, c = g >> 7, k = g & 127;
        w1bt[c * 128 + k] = f2bf(mw1[(size_t)(128 + k) * HID + c]);
    } else if (gid < 49152) {
        int g = gid - 32768, c = g >> 7, k = g & 127;
        w2t[c * 128 + k] = f2bf(mw2[(size_t)k * HID + c]);
    } else if (gid < 81920) {
        int g = gid - 49152, c = g >> 8, k = g & 255;
        uw1t[c * 256 + k] = f2bf(uw1[(size_t)k * HID + c]);
    } else if (gid < 98304) {
        int g = gid - 81920, c = g >> 7, k = g & 127;
        uw2t[c * 128 + k] = f2bf(uw2[(size_t)k * HID + c]);
    } else if (gid < 98432) {
        int c = gid - 98304;
        tailpack[c] = make_float4(mw1[(size_t)256 * HID + c],
                                  mw1[(size_t)257 * HID + c],
                                  mw1[(size_t)258 * HID + c],
                                  mb1[c]);
    } else if (gid < 110936) {
        counts4[gid - 98432] = make_float4(0.f, 0.f, 0.f, 0.f);
    } else if (gid < 123440) {
        cursor4[gid - 110936] = make_float4(0.f, 0.f, 0.f, 0.f);
    } else if (gid < 1723440) {
        T4[gid - 123440] = make_float4(0.f, 0.f, 0.f, 0.f);
    }
}

// ---------------- CSR build ----------------
__global__ __launch_bounds__(256) void hist_kernel(
    const int* __restrict__ ei, uint* __restrict__ counts)
{
    int e = blockIdx.x * 256 + threadIdx.x;
    if (e < N_EDGES) atomicAdd(&counts[ei[N_EDGES + e]], 1u);
}

#define SCAN_B 196
__global__ __launch_bounds__(256) void scan1_kernel(
    const uint* __restrict__ counts, uint* __restrict__ partials)
{
    __shared__ uint sm[256];
    int b = blockIdx.x, tid = threadIdx.x;
    int i = b * 256 + tid;
    sm[tid] = (i < N_NODES) ? counts[i] : 0u;
    __syncthreads();
    for (int off = 128; off > 0; off >>= 1) {
        if (tid < off) sm[tid] += sm[tid + off];
        __syncthreads();
    }
    if (tid == 0) partials[b] = sm[0];
}

// scan of partials folded in: every block scans the 196 partials locally.
__global__ __launch_bounds__(256) void scan3_kernel(
    const uint* __restrict__ counts, const uint* __restrict__ partials,
    uint* __restrict__ rowptr)
{
    __shared__ uint sp[256];
    __shared__ uint sm[256];
    __shared__ uint base_s;
    int b = blockIdx.x, tid = threadIdx.x;
    uint pv = (tid < SCAN_B) ? partials[tid] : 0u;
    sp[tid] = pv;
    __syncthreads();
    for (int off = 1; off < 256; off <<= 1) {
        uint t = (tid >= off) ? sp[tid - off] : 0u;
        __syncthreads();
        sp[tid] += t;
        __syncthreads();
    }
    if (tid == (uint)b) base_s = sp[tid] - pv;   // exclusive prefix for this block
    int i = b * 256 + tid;
    uint v = (i < N_NODES) ? counts[i] : 0u;
    sm[tid] = v;
    __syncthreads();
    for (int off = 1; off < 256; off <<= 1) {
        uint t = (tid >= off) ? sm[tid - off] : 0u;
        __syncthreads();
        sm[tid] += t;
        __syncthreads();
    }
    if (i < N_NODES) rowptr[i] = sm[tid] - v + base_s;
    if (i == N_NODES - 1) rowptr[N_NODES] = N_EDGES;
}

// ---- build: scatter packed payload {src,dst,ea01,ea2} to dst-sorted position -
__global__ __launch_bounds__(256) void build_kernel(
    const int* __restrict__ ei, const float* __restrict__ ea,
    const uint* __restrict__ rowptr, uint* __restrict__ cursor,
    uint4* __restrict__ epack)
{
    int e = blockIdx.x * 256 + threadIdx.x;
    if (e >= N_EDGES) return;
    int src = ei[e];
    int dst = ei[N_EDGES + e];
    uint pos = rowptr[dst] + atomicAdd(&cursor[dst], 1u);
    uint4 p;
    p.x = (uint)src;
    p.y = (uint)dst;
    p.z = (uint)f2bf(ea[(size_t)e * 3 + 0]) | ((uint)f2bf(ea[(size_t)e * 3 + 1]) << 16);
    p.w = (uint)f2bf(ea[(size_t)e * 3 + 2]);
    epack[pos] = p;
}

// ---------------- pre: h = x@enc_w+enc_b (bf16); A = h@W1a; B = h@W1b ----------
__global__ __launch_bounds__(512, 2) void pre_kernel(
    const float* __restrict__ x, const float* __restrict__ enc_w,
    const float* __restrict__ enc_b,
    const ushort* __restrict__ w1at, const ushort* __restrict__ w1bt,
    ushort* __restrict__ hb, ushort* __restrict__ Abuf, ushort* __restrict__ Bbuf)
{
    __shared__ __align__(16) ushort htile[64][152];
    __shared__ __align__(16) ushort ABst[64][280];
    __shared__ float x_s[64][6];
    __shared__ float encw_s[640];
    __shared__ float encb_s[128];

    int tid = threadIdx.x;
    int n0 = blockIdx.x * 64;

    if (tid < 320) {
        int nl = tid / 5, k = tid % 5;
        int n = n0 + nl;
        x_s[nl][k] = (n < N_NODES) ? x[(size_t)n * 5 + k] : 0.f;
    }
    if (tid < 128) encb_s[tid] = enc_b[tid];
    encw_s[tid] = enc_w[tid];
    if (tid < 128) encw_s[512 + tid] = enc_w[512 + tid];
    __syncthreads();

    {
        int el = tid >> 3, q = tid & 7;
        int c0 = q * 16;
        union { ushort u[16]; uint4 v[2]; } hv;
#pragma unroll
        for (int c = 0; c < 16; ++c) {
            int j = c0 + c;
            float acc = encb_s[j];
#pragma unroll
            for (int k = 0; k < 5; ++k)
                acc = fmaf(x_s[el][k], encw_s[k * 128 + j], acc);
            hv.u[c] = f2bf(acc);
        }
        *(uint4*)&htile[el][c0]     = hv.v[0];
        *(uint4*)&htile[el][c0 + 8] = hv.v[1];
        int n = n0 + el;
        if (n < N_NODES) {
            uint4* gp = (uint4*)(hb + (size_t)n * HID + c0);
            gp[0] = hv.v[0];
            gp[1] = hv.v[1];
        }
    }
    __syncthreads();

    int lane = tid & 63;
    int wid  = tid >> 6;
    int cg   = wid & 3;
    int mg   = wid >> 2;
    int lhi  = lane >> 4;
    int llo  = lane & 15;
    int col0 = cg * 32 + llo;
    int col1 = cg * 32 + 16 + llo;

    {
        floatx4 acc[2][2];
#pragma unroll
        for (int lm = 0; lm < 2; ++lm)
#pragma unroll
            for (int r = 0; r < 4; ++r) { acc[lm][0][r] = 0.f; acc[lm][1][r] = 0.f; }
        const ushort* bp0 = w1at + (size_t)col0 * 128 + lhi * 8;
        const ushort* bp1 = w1at + (size_t)col1 * 128 + lhi * 8;
#pragma unroll
        for (int kk = 0; kk < 4; ++kk) {
            short8 bf0 = *(const short8*)(bp0 + kk * 32);
            short8 bf1 = *(const short8*)(bp1 + kk * 32);
#pragma unroll
            for (int lm = 0; lm < 2; ++lm) {
                int row = (mg * 2 + lm) * 16 + llo;
                short8 a = *(const short8*)((const char*)htile + (size_t)row * 304 + kk * 64 + lhi * 16);
                acc[lm][0] = __builtin_amdgcn_mfma_f32_16x16x32_bf16(a, bf0, acc[lm][0], 0, 0, 0);
                acc[lm][1] = __builtin_amdgcn_mfma_f32_16x16x32_bf16(a, bf1, acc[lm][1], 0, 0, 0);
            }
        }
#pragma unroll
        for (int lm = 0; lm < 2; ++lm)
#pragma unroll
            for (int r = 0; r < 4; ++r) {
                int row = (mg * 2 + lm) * 16 + lhi * 4 + r;
                ABst[row][col0] = f2bf(acc[lm][0][r]);
                ABst[row][col1] = f2bf(acc[lm][1][r]);
            }
    }
    {
        floatx4 acc[2][2];
#pragma unroll
        for (int lm = 0; lm < 2; ++lm)
#pragma unroll
            for (int r = 0; r < 4; ++r) { acc[lm][0][r] = 0.f; acc[lm][1][r] = 0.f; }
        const ushort* bp0 = w1bt + (size_t)col0 * 128 + lhi * 8;
        const ushort* bp1 = w1bt + (size_t)col1 * 128 + lhi * 8;
#pragma unroll
        for (int kk = 0; kk < 4; ++kk) {
            short8 bf0 = *(const short8*)(bp0 + kk * 32);
            short8 bf1 = *(const short8*)(bp1 + kk * 32);
#pragma unroll
            for (int lm = 0; lm < 2; ++lm) {
                int row = (mg * 2 + lm) * 16 + llo;
                short8 a = *(const short8*)((const char*)htile + (size_t)row * 304 + kk * 64 + lhi * 16);
                acc[lm][0] = __builtin_amdgcn_mfma_f32_16x16x32_bf16(a, bf0, acc[lm][0], 0, 0, 0);
                acc[lm][1] = __builtin_amdgcn_mfma_f32_16x16x32_bf16(a, bf1, acc[lm][1], 0, 0, 0);
            }
        }
#pragma unroll
        for (int lm = 0; lm < 2; ++lm)
#pragma unroll
            for (int r = 0; r < 4; ++r) {
                int row = (mg * 2 + lm) * 16 + lhi * 4 + r;
                ABst[row][128 + col0] = f2bf(acc[lm][0][r]);
                ABst[row][128 + col1] = f2bf(acc[lm][1][r]);
            }
    }
    __syncthreads();

    {
        int el = tid >> 3, q = tid & 7;
        int n = n0 + el;
        if (n < N_NODES) {
            uint4* ga = (uint4*)(Abuf + (size_t)n * HID + q * 16);
            ga[0] = *(uint4*)&ABst[el][q * 16];
            ga[1] = *(uint4*)&ABst[el][q * 16 + 8];
            uint4* gb = (uint4*)(Bbuf + (size_t)n * HID + q * 16);
            gb[0] = *(uint4*)&ABst[el][128 + q * 16];
            gb[1] = *(uint4*)&ABst[el][128 + q * 16 + 8];
        }
    }
}

// ---- edge: stream payload; per-wave 80-edge window; cols {2*lane, 2*lane+1};
//      single uint B/A loads; interior runs -> float2 store; boundaries -> atomics
#define EPB 640
#define EPW 80
__global__ __launch_bounds__(512) void edge_kernel(
    const ushort* __restrict__ Abuf, const ushort* __restrict__ Bbuf,
    const uint4* __restrict__ epack, const float4* __restrict__ tailpack,
    float* __restrict__ T)
{
    __shared__ __align__(16) uint4 ep_s[EPB];

    int tid = threadIdx.x;
    size_t p0 = (size_t)blockIdx.x * EPB;
    ep_s[tid] = epack[p0 + tid];
    if (tid < EPB - 512) ep_s[512 + tid] = epack[p0 + 512 + tid];
    __syncthreads();

    int wid = tid >> 6, lane = tid & 63;
    int base = wid * EPW;
    float4 tp0 = tailpack[2 * lane];
    float4 tp1 = tailpack[2 * lane + 1];

    uint4 p = ep_s[base];
    int prev = (int)p.y;
    uint au = ((const uint*)(Abuf + (size_t)prev * HID))[lane];
    float a0 = bf2f((ushort)(au & 0xffffu));
    float a1 = bf2f((ushort)(au >> 16));
    float acc0 = 0.f, acc1 = 0.f;
    bool first = true;

#pragma unroll 4
    for (int j = 0; j < EPW; ++j) {
        p = ep_s[base + j];
        int d = (int)p.y;
        if (d != prev) {                    // wave-uniform branch
            float* Tr = T + (size_t)prev * HID + 2 * lane;
            if (first) {
                atomicAdd(Tr + 0, acc0);
                atomicAdd(Tr + 1, acc1);
            } else {
                *(float2*)Tr = make_float2(acc0, acc1);   // run interior: exclusive
            }
            first = false;
            acc0 = 0.f; acc1 = 0.f;
            prev = d;
            au = ((const uint*)(Abuf + (size_t)d * HID))[lane];
            a0 = bf2f((ushort)(au & 0xffffu));
            a1 = bf2f((ushort)(au >> 16));
        }
        uint bu = ((const uint*)(Bbuf + (size_t)p.x * HID))[lane];
        float e0 = bf2f((ushort)(p.z & 0xffffu));
        float e1 = bf2f((ushort)(p.z >> 16));
        float e2 = bf2f((ushort)(p.w & 0xffffu));
        float t0 = fmaf(e0, tp0.x, fmaf(e1, tp0.y, fmaf(e2, tp0.z, tp0.w)))
                   + a0 + bf2f((ushort)(bu & 0xffffu));
        float t1 = fmaf(e0, tp1.x, fmaf(e1, tp1.y, fmaf(e2, tp1.z, tp1.w)))
                   + a1 + bf2f((ushort)(bu >> 16));
        acc0 += fmaxf(t0, 0.f);
        acc1 += fmaxf(t1, 0.f);
    }
    float* Tr = T + (size_t)prev * HID + 2 * lane;   // last run: boundary
    atomicAdd(Tr + 0, acc0);
    atomicAdd(Tr + 1, acc1);
}

// ---- upd: aggr = T@W2 + deg*b2; node MLP + residual + decode.
//      LDS aliased: t1 overwrites Tt; hf overwrites comb h-half. 52.3KB -> 3/CU.
__global__ __launch_bounds__(512, 6) void upd_kernel(
    const ushort* __restrict__ hb, const float* __restrict__ T,
    const uint* __restrict__ rowptr,
    const ushort* __restrict__ w2t, const float* __restrict__ mb2,
    const float* __restrict__ ub1, const float* __restrict__ ub2,
    const ushort* __restrict__ uw1t, const ushort* __restrict__ uw2t,
    const float* __restrict__ dec_w, const float* __restrict__ dec_b,
    float* __restrict__ out)
{
    __shared__ __align__(16) ushort comb[64][280];   // [h | aggr] -> [hf | aggr]
    __shared__ __align__(16) ushort Tt[64][136];     // T bf16 -> t1, pitch 272B
    __shared__ float deg_s[64];

    int tid = threadIdx.x;
    int n0 = blockIdx.x * 64;

    {
        int el = tid >> 3, q = tid & 7;
        int n = n0 + el;
        if (n < N_NODES) {
            const uint4* gp = (const uint4*)(hb + (size_t)n * HID + q * 16);
            uint4* lp = (uint4*)&comb[el][q * 16];
            lp[0] = gp[0]; lp[1] = gp[1];
            const float4* tpp = (const float4*)(T + (size_t)n * HID + q * 16);
            union { ushort u[16]; uint4 v[2]; } tv;
#pragma unroll
            for (int i = 0; i < 4; ++i) {
                float4 v = tpp[i];
                tv.u[i * 4 + 0] = f2bf(v.x);
                tv.u[i * 4 + 1] = f2bf(v.y);
                tv.u[i * 4 + 2] = f2bf(v.z);
                tv.u[i * 4 + 3] = f2bf(v.w);
            }
            *(uint4*)&Tt[el][q * 16]     = tv.v[0];
            *(uint4*)&Tt[el][q * 16 + 8] = tv.v[1];
        } else {
            uint4 z = make_uint4(0, 0, 0, 0);
            uint4* lp = (uint4*)&comb[el][q * 16];
            lp[0] = z; lp[1] = z;
            *(uint4*)&Tt[el][q * 16]     = z;
            *(uint4*)&Tt[el][q * 16 + 8] = z;
        }
        if (tid < 64) {
            int n2 = n0 + tid;
            deg_s[tid] = (n2 < N_NODES) ? (float)(rowptr[n2 + 1] - rowptr[n2]) : 0.f;
        }
    }
    __syncthreads();

    int lane = tid & 63;
    int wid  = tid >> 6;
    int cg   = wid & 3;
    int mg   = wid >> 2;
    int lhi  = lane >> 4;
    int llo  = lane & 15;
    int col0 = cg * 32 + llo;
    int col1 = cg * 32 + 16 + llo;

    // ---- aggr = Tt @ W2 + deg*b2 -> comb[.,128:256] ----
    {
        floatx4 acc[2][2];
        float b0 = mb2[col0], b1 = mb2[col1];
#pragma unroll
        for (int lm = 0; lm < 2; ++lm)
#pragma unroll
            for (int r = 0; r < 4; ++r) {
                int row = (mg * 2 + lm) * 16 + lhi * 4 + r;
                acc[lm][0][r] = deg_s[row] * b0;
                acc[lm][1][r] = deg_s[row] * b1;
            }
        const ushort* bp0 = w2t + (size_t)col0 * 128 + lhi * 8;
        const ushort* bp1 = w2t + (size_t)col1 * 128 + lhi * 8;
#pragma unroll
        for (int kk = 0; kk < 4; ++kk) {
            short8 bf0 = *(const short8*)(bp0 + kk * 32);
            short8 bf1 = *(const short8*)(bp1 + kk * 32);
#pragma unroll
            for (int lm = 0; lm < 2; ++lm) {
                int row = (mg * 2 + lm) * 16 + llo;
                short8 a = *(const short8*)((const char*)Tt + (size_t)row * 272 + kk * 64 + lhi * 16);
                acc[lm][0] = __builtin_amdgcn_mfma_f32_16x16x32_bf16(a, bf0, acc[lm][0], 0, 0, 0);
                acc[lm][1] = __builtin_amdgcn_mfma_f32_16x16x32_bf16(a, bf1, acc[lm][1], 0, 0, 0);
            }
        }
#pragma unroll
        for (int lm = 0; lm < 2; ++lm)
#pragma unroll
            for (int r = 0; r < 4; ++r) {
                int row = (mg * 2 + lm) * 16 + lhi * 4 + r;
                comb[row][128 + col0] = f2bf(acc[lm][0][r]);
                comb[row][128 + col1] = f2bf(acc[lm][1][r]);
            }
    }
    __syncthreads();

    // ---- layer 1: comb @ uw1 + ub1, relu -> Tt (overwrites T data, now dead) --
    {
        floatx4 acc[2][2];
        float b0 = ub1[col0], b1 = ub1[col1];
#pragma unroll
        for (int lm = 0; lm < 2; ++lm)
#pragma unroll
            for (int r = 0; r < 4; ++r) { acc[lm][0][r] = b0; acc[lm][1][r] = b1; }
        const ushort* bp0 = uw1t + (size_t)col0 * 256 + lhi * 8;
        const ushort* bp1 = uw1t + (size_t)col1 * 256 + lhi * 8;
#pragma unroll
        for (int kk = 0; kk < 8; ++kk) {
            short8 bf0 = *(const short8*)(bp0 + kk * 32);
            short8 bf1 = *(const short8*)(bp1 + kk * 32);
#pragma unroll
            for (int lm = 0; lm < 2; ++lm) {
                int row = (mg * 2 + lm) * 16 + llo;
                short8 a = *(const short8*)((const char*)comb + (size_t)row * 560 + kk * 64 + lhi * 16);
                acc[lm][0] = __builtin_amdgcn_mfma_f32_16x16x32_bf16(a, bf0, acc[lm][0], 0, 0, 0);
                acc[lm][1] = __builtin_amdgcn_mfma_f32_16x16x32_bf16(a, bf1, acc[lm][1], 0, 0, 0);
            }
        }
        __syncthreads();   // all aggr-GEMM reads of Tt are done (sync above), and
                           // all layer-1 reads of comb complete before t1 write? reads
                           // are per-wave done; cross-wave comb reads finished at the
                           // barrier that follows. Writes below touch Tt only.
#pragma unroll
        for (int lm = 0; lm < 2; ++lm)
#pragma unroll
            for (int r = 0; r < 4; ++r) {
                int row = (mg * 2 + lm) * 16 + lhi * 4 + r;
                Tt[row][col0] = f2bf(fmaxf(acc[lm][0][r], 0.f));
                Tt[row][col1] = f2bf(fmaxf(acc[lm][1][r], 0.f));
            }
    }
    __syncthreads();

    // ---- layer 2 + residual -> comb[.,0:128] (hf over h, same-thread elements) -
    {
        floatx4 acc[2][2];
        float b0 = ub2[col0], b1 = ub2[col1];
#pragma unroll
        for (int lm = 0; lm < 2; ++lm)
#pragma unroll
            for (int r = 0; r < 4; ++r) { acc[lm][0][r] = b0; acc[lm][1][r] = b1; }
        const ushort* bp0 = uw2t + (size_t)col0 * 128 + lhi * 8;
        const ushort* bp1 = uw2t + (size_t)col1 * 128 + lhi * 8;
#pragma unroll
        for (int kk = 0; kk < 4; ++kk) {
            short8 bf0 = *(const short8*)(bp0 + kk * 32);
            short8 bf1 = *(const short8*)(bp1 + kk * 32);
#pragma unroll
            for (int lm = 0; lm < 2; ++lm) {
                int row = (mg * 2 + lm) * 16 + llo;
                short8 a = *(const short8*)((const char*)Tt + (size_t)row * 272 + kk * 64 + lhi * 16);
                acc[lm][0] = __builtin_amdgcn_mfma_f32_16x16x32_bf16(a, bf0, acc[lm][0], 0, 0, 0);
                acc[lm][1] = __builtin_amdgcn_mfma_f32_16x16x32_bf16(a, bf1, acc[lm][1], 0, 0, 0);
            }
        }
#pragma unroll
        for (int lm = 0; lm < 2; ++lm)
#pragma unroll
            for (int r = 0; r < 4; ++r) {
                int row = (mg * 2 + lm) * 16 + lhi * 4 + r;
                float h0 = bf2f(comb[row][col0]);
                float h1 = bf2f(comb[row][col1]);
                comb[row][col0] = f2bf(h0 + acc[lm][0][r]);
                comb[row][col1] = f2bf(h1 + acc[lm][1][r]);
            }
    }
    __syncthreads();

    // ---- decode: out[n] = hf @ dec_w + dec_b ----
    if (tid < 320) {
        int nl = tid / 5;
        int c = tid % 5;
        int n = n0 + nl;
        if (n < N_NODES) {
            float acc0 = dec_b[c];
            for (int j = 0; j < HID; ++j)
                acc0 = fmaf(bf2f(comb[nl][j]), dec_w[(size_t)j * 5 + c], acc0);
            out[(size_t)n * 5 + c] = acc0;
        }
    }
}

extern "C" void kernel_launch(void* const* d_in, const int* in_sizes, int n_in,
                              void* d_out, int out_size, void* d_ws, size_t ws_size,
                              hipStream_t stream) {
    const float* x     = (const float*)d_in[0];
    const int*   ei    = (const int*)d_in[1];
    const float* ea    = (const float*)d_in[2];
    const float* enc_w = (const float*)d_in[3];
    const float* enc_b = (const float*)d_in[4];
    const float* dec_w = (const float*)d_in[5];
    const float* dec_b = (const float*)d_in[6];
    // Only layer l=3 contributes (loop overwrites h_update; h never changes).
    const float* mw1 = (const float*)d_in[7]  + (size_t)3 * 259 * HID;
    const float* mb1 = (const float*)d_in[8]  + (size_t)3 * HID;
    const float* mw2 = (const float*)d_in[9]  + (size_t)3 * HID * HID;
    const float* mb2 = (const float*)d_in[10] + (size_t)3 * HID;
    const float* uw1 = (const float*)d_in[11] + (size_t)3 * 256 * HID;
    const float* ub1 = (const float*)d_in[12] + (size_t)3 * HID;
    const float* uw2 = (const float*)d_in[13] + (size_t)3 * HID * HID;
    const float* ub2 = (const float*)d_in[14] + (size_t)3 * HID;

    char* w = (char*)d_ws;
    ushort* hb     = (ushort*)w;  w += (size_t)N_NODES * HID * 2;   // 12.8MB
    ushort* Abuf   = (ushort*)w;  w += (size_t)N_NODES * HID * 2;   // 12.8MB
    ushort* Bbuf   = (ushort*)w;  w += (size_t)N_NODES * HID * 2;   // 12.8MB
    float*  T      = (float*)w;   w += (size_t)N_NODES * HID * 4;   // 25.6MB
    uint*   counts = (uint*)w;    w += (size_t)50016 * 4;
    uint*   cursor = (uint*)w;    w += (size_t)50016 * 4;
    uint*   rowptr = (uint*)w;    w += (size_t)50016 * 4;
    uint*   partials=(uint*)w;    w += (size_t)256 * 4;
    uint4*  epack  = (uint4*)w;   w += (size_t)N_EDGES * 16;        // 12.8MB
    ushort* w1at   = (ushort*)w;  w += (size_t)128 * 128 * 2;
    ushort* w1bt   = (ushort*)w;  w += (size_t)128 * 128 * 2;
    ushort* w2t    = (ushort*)w;  w += (size_t)128 * 128 * 2;
    ushort* uw1t   = (ushort*)w;  w += (size_t)128 * 256 * 2;
    ushort* uw2t   = (ushort*)w;  w += (size_t)128 * 128 * 2;
    float4* tailpack = (float4*)w; w += (size_t)128 * 16;
    float*  out    = (float*)d_out;

    prep_kernel<<<(1723440 + 255) / 256, 256, 0, stream>>>(
        mw1, mb1, mw2, uw1, uw2, w1at, w1bt, w2t, uw1t, uw2t, tailpack,
        (float4*)counts, (float4*)cursor, (float4*)T);
    hist_kernel<<<(N_EDGES + 255) / 256, 256, 0, stream>>>(ei, counts);
    scan1_kernel<<<SCAN_B, 256, 0, stream>>>(counts, partials);
    scan3_kernel<<<SCAN_B, 256, 0, stream>>>(counts, partials, rowptr);
    build_kernel<<<(N_EDGES + 255) / 256, 256, 0, stream>>>(ei, ea, rowptr, cursor, epack);
    pre_kernel<<<(N_NODES + 63) / 64, 512, 0, stream>>>(
        x, enc_w, enc_b, w1at, w1bt, hb, Abuf, Bbuf);
    edge_kernel<<<N_EDGES / EPB, 512, 0, stream>>>(Abuf, Bbuf, epack, tailpack, T);
    upd_kernel<<<(N_NODES + 63) / 64, 512, 0, stream>>>(
        hb, T, rowptr, w2t, mb2, ub1, ub2, uw1t, uw2t, dec_w, dec_b, out);
}

// Round 11
// 221.884 us; speedup vs baseline: 1.2522x; 1.1177x over previous
//
#include <hip/hip_runtime.h>
#include <hip/hip_bf16.h>

#define N_NODES 50000
#define N_EDGES 800000
#define HID 128

using short8  = __attribute__((ext_vector_type(8))) short;
using floatx4 = __attribute__((ext_vector_type(4))) float;

__device__ __forceinline__ float bf2f(ushort u) {
    union { uint u32; float f; } v; v.u32 = ((uint)u) << 16; return v.f;
}
__device__ __forceinline__ ushort f2bf(float f) {
    __hip_bfloat16 b = __float2bfloat16(f);
    return *reinterpret_cast<ushort*>(&b);
}

// ---- fused prep: weight transpose/bf16 + tailpack + dec_wt + zero(counts,cursor,T)
__global__ __launch_bounds__(256) void prep_kernel(
    const float* __restrict__ mw1, const float* __restrict__ mb1,
    const float* __restrict__ mw2,
    const float* __restrict__ uw1, const float* __restrict__ uw2,
    const float* __restrict__ dec_w,
    ushort* __restrict__ w1at, ushort* __restrict__ w1bt,
    ushort* __restrict__ w2t,
    ushort* __restrict__ uw1t, ushort* __restrict__ uw2t,
    ushort* __restrict__ dec_wt,
    float4* __restrict__ tailpack,
    float4* __restrict__ counts4, float4* __restrict__ cursor4,
    float4* __restrict__ T4)
{
    int gid = blockIdx.x * 256 + threadIdx.x;
    if (gid < 16384) {
        int c = gid >> 7, k = gid & 127;
        w1at[c * 128 + k] = f2bf(mw1[(size_t)k * HID + c]);
    } else if (gid < 32768) {
        int g = gid - 16384, c = g >> 7, k = g & 127;
        w1bt[c * 128 + k] = f2bf(mw1[(size_t)(128 + k) * HID + c]);
    } else if (gid < 49152) {
        int g = gid - 32768, c = g >> 7, k = g & 127;
        w2t[c * 128 + k] = f2bf(mw2[(size_t)k * HID + c]);
    } else if (gid < 81920) {
        int g = gid - 49152, c = g >> 8, k = g & 255;
        uw1t[c * 256 + k] = f2bf(uw1[(size_t)k * HID + c]);
    } else if (gid < 98304) {
        int g = gid - 81920, c = g >> 7, k = g & 127;
        uw2t[c * 128 + k] = f2bf(uw2[(size_t)k * HID + c]);
    } else if (gid < 98432) {
        int c = gid - 98304;
        tailpack[c] = make_float4(mw1[(size_t)256 * HID + c],
                                  mw1[(size_t)257 * HID + c],
                                  mw1[(size_t)258 * HID + c],
                                  mb1[c]);
    } else if (gid < 100480) {
        int g = gid - 98432, c = g >> 7, k = g & 127;    // dec_wt [16][128], pad 0
        dec_wt[c * 128 + k] = (c < 5) ? f2bf(dec_w[(size_t)k * 5 + c]) : (ushort)0;
    } else if (gid < 112984) {
        counts4[gid - 100480] = make_float4(0.f, 0.f, 0.f, 0.f);
    } else if (gid < 125488) {
        cursor4[gid - 112984] = make_float4(0.f, 0.f, 0.f, 0.f);
    } else if (gid < 1725488) {
        T4[gid - 125488] = make_float4(0.f, 0.f, 0.f, 0.f);
    }
}

// ---------------- CSR build ----------------
__global__ __launch_bounds__(256) void hist_kernel(
    const int* __restrict__ ei, uint* __restrict__ counts)
{
    int e = blockIdx.x * 256 + threadIdx.x;
    if (e < N_EDGES) atomicAdd(&counts[ei[N_EDGES + e]], 1u);
}

#define SCAN_B 196
__global__ __launch_bounds__(256) void scan1_kernel(
    const uint* __restrict__ counts, uint* __restrict__ partials)
{
    __shared__ uint sm[256];
    int b = blockIdx.x, tid = threadIdx.x;
    int i = b * 256 + tid;
    sm[tid] = (i < N_NODES) ? counts[i] : 0u;
    __syncthreads();
    for (int off = 128; off > 0; off >>= 1) {
        if (tid < off) sm[tid] += sm[tid + off];
        __syncthreads();
    }
    if (tid == 0) partials[b] = sm[0];
}

// scan of partials folded in: every block scans the 196 partials locally.
__global__ __launch_bounds__(256) void scan3_kernel(
    const uint* __restrict__ counts, const uint* __restrict__ partials,
    uint* __restrict__ rowptr)
{
    __shared__ uint sp[256];
    __shared__ uint sm[256];
    __shared__ uint base_s;
    int b = blockIdx.x, tid = threadIdx.x;
    uint pv = (tid < SCAN_B) ? partials[tid] : 0u;
    sp[tid] = pv;
    __syncthreads();
    for (int off = 1; off < 256; off <<= 1) {
        uint t = (tid >= off) ? sp[tid - off] : 0u;
        __syncthreads();
        sp[tid] += t;
        __syncthreads();
    }
    if (tid == (uint)b) base_s = sp[tid] - pv;   // exclusive prefix for this block
    int i = b * 256 + tid;
    uint v = (i < N_NODES) ? counts[i] : 0u;
    sm[tid] = v;
    __syncthreads();
    for (int off = 1; off < 256; off <<= 1) {
        uint t = (tid >= off) ? sm[tid - off] : 0u;
        __syncthreads();
        sm[tid] += t;
        __syncthreads();
    }
    if (i < N_NODES) rowptr[i] = sm[tid] - v + base_s;
    if (i == N_NODES - 1) rowptr[N_NODES] = N_EDGES;
}

// ---- build: scatter packed payload {src,dst,ea01,ea2} to dst-sorted position -
__global__ __launch_bounds__(256) void build_kernel(
    const int* __restrict__ ei, const float* __restrict__ ea,
    const uint* __restrict__ rowptr, uint* __restrict__ cursor,
    uint4* __restrict__ epack)
{
    int e = blockIdx.x * 256 + threadIdx.x;
    if (e >= N_EDGES) return;
    int src = ei[e];
    int dst = ei[N_EDGES + e];
    uint pos = rowptr[dst] + atomicAdd(&cursor[dst], 1u);
    uint4 p;
    p.x = (uint)src;
    p.y = (uint)dst;
    p.z = (uint)f2bf(ea[(size_t)e * 3 + 0]) | ((uint)f2bf(ea[(size_t)e * 3 + 1]) << 16);
    p.w = (uint)f2bf(ea[(size_t)e * 3 + 2]);
    epack[pos] = p;
}

// ---------------- pre: h = x@enc_w+enc_b (bf16); A = h@W1a; B = h@W1b ----------
__global__ __launch_bounds__(512, 2) void pre_kernel(
    const float* __restrict__ x, const float* __restrict__ enc_w,
    const float* __restrict__ enc_b,
    const ushort* __restrict__ w1at, const ushort* __restrict__ w1bt,
    ushort* __restrict__ hb, ushort* __restrict__ Abuf, ushort* __restrict__ Bbuf)
{
    __shared__ __align__(16) ushort htile[64][152];
    __shared__ __align__(16) ushort ABst[64][280];
    __shared__ float x_s[64][6];
    __shared__ float encw_s[640];
    __shared__ float encb_s[128];

    int tid = threadIdx.x;
    int n0 = blockIdx.x * 64;

    if (tid < 320) {
        int nl = tid / 5, k = tid % 5;
        int n = n0 + nl;
        x_s[nl][k] = (n < N_NODES) ? x[(size_t)n * 5 + k] : 0.f;
    }
    if (tid < 128) encb_s[tid] = enc_b[tid];
    encw_s[tid] = enc_w[tid];
    if (tid < 128) encw_s[512 + tid] = enc_w[512 + tid];
    __syncthreads();

    {
        int el = tid >> 3, q = tid & 7;
        int c0 = q * 16;
        union { ushort u[16]; uint4 v[2]; } hv;
#pragma unroll
        for (int c = 0; c < 16; ++c) {
            int j = c0 + c;
            float acc = encb_s[j];
#pragma unroll
            for (int k = 0; k < 5; ++k)
                acc = fmaf(x_s[el][k], encw_s[k * 128 + j], acc);
            hv.u[c] = f2bf(acc);
        }
        *(uint4*)&htile[el][c0]     = hv.v[0];
        *(uint4*)&htile[el][c0 + 8] = hv.v[1];
        int n = n0 + el;
        if (n < N_NODES) {
            uint4* gp = (uint4*)(hb + (size_t)n * HID + c0);
            gp[0] = hv.v[0];
            gp[1] = hv.v[1];
        }
    }
    __syncthreads();

    int lane = tid & 63;
    int wid  = tid >> 6;
    int cg   = wid & 3;
    int mg   = wid >> 2;
    int lhi  = lane >> 4;
    int llo  = lane & 15;
    int col0 = cg * 32 + llo;
    int col1 = cg * 32 + 16 + llo;

    {
        floatx4 acc[2][2];
#pragma unroll
        for (int lm = 0; lm < 2; ++lm)
#pragma unroll
            for (int r = 0; r < 4; ++r) { acc[lm][0][r] = 0.f; acc[lm][1][r] = 0.f; }
        const ushort* bp0 = w1at + (size_t)col0 * 128 + lhi * 8;
        const ushort* bp1 = w1at + (size_t)col1 * 128 + lhi * 8;
#pragma unroll
        for (int kk = 0; kk < 4; ++kk) {
            short8 bf0 = *(const short8*)(bp0 + kk * 32);
            short8 bf1 = *(const short8*)(bp1 + kk * 32);
#pragma unroll
            for (int lm = 0; lm < 2; ++lm) {
                int row = (mg * 2 + lm) * 16 + llo;
                short8 a = *(const short8*)((const char*)htile + (size_t)row * 304 + kk * 64 + lhi * 16);
                acc[lm][0] = __builtin_amdgcn_mfma_f32_16x16x32_bf16(a, bf0, acc[lm][0], 0, 0, 0);
                acc[lm][1] = __builtin_amdgcn_mfma_f32_16x16x32_bf16(a, bf1, acc[lm][1], 0, 0, 0);
            }
        }
#pragma unroll
        for (int lm = 0; lm < 2; ++lm)
#pragma unroll
            for (int r = 0; r < 4; ++r) {
                int row = (mg * 2 + lm) * 16 + lhi * 4 + r;
                ABst[row][col0] = f2bf(acc[lm][0][r]);
                ABst[row][col1] = f2bf(acc[lm][1][r]);
            }
    }
    {
        floatx4 acc[2][2];
#pragma unroll
        for (int lm = 0; lm < 2; ++lm)
#pragma unroll
            for (int r = 0; r < 4; ++r) { acc[lm][0][r] = 0.f; acc[lm][1][r] = 0.f; }
        const ushort* bp0 = w1bt + (size_t)col0 * 128 + lhi * 8;
        const ushort* bp1 = w1bt + (size_t)col1 * 128 + lhi * 8;
#pragma unroll
        for (int kk = 0; kk < 4; ++kk) {
            short8 bf0 = *(const short8*)(bp0 + kk * 32);
            short8 bf1 = *(const short8*)(bp1 + kk * 32);
#pragma unroll
            for (int lm = 0; lm < 2; ++lm) {
                int row = (mg * 2 + lm) * 16 + llo;
                short8 a = *(const short8*)((const char*)htile + (size_t)row * 304 + kk * 64 + lhi * 16);
                acc[lm][0] = __builtin_amdgcn_mfma_f32_16x16x32_bf16(a, bf0, acc[lm][0], 0, 0, 0);
                acc[lm][1] = __builtin_amdgcn_mfma_f32_16x16x32_bf16(a, bf1, acc[lm][1], 0, 0, 0);
            }
        }
#pragma unroll
        for (int lm = 0; lm < 2; ++lm)
#pragma unroll
            for (int r = 0; r < 4; ++r) {
                int row = (mg * 2 + lm) * 16 + lhi * 4 + r;
                ABst[row][128 + col0] = f2bf(acc[lm][0][r]);
                ABst[row][128 + col1] = f2bf(acc[lm][1][r]);
            }
    }
    __syncthreads();

    {
        int el = tid >> 3, q = tid & 7;
        int n = n0 + el;
        if (n < N_NODES) {
            uint4* ga = (uint4*)(Abuf + (size_t)n * HID + q * 16);
            ga[0] = *(uint4*)&ABst[el][q * 16];
            ga[1] = *(uint4*)&ABst[el][q * 16 + 8];
            uint4* gb = (uint4*)(Bbuf + (size_t)n * HID + q * 16);
            gb[0] = *(uint4*)&ABst[el][128 + q * 16];
            gb[1] = *(uint4*)&ABst[el][128 + q * 16 + 8];
        }
    }
}

// ---- edge: stream payload; per-wave 40-edge window; cols {2*lane, 2*lane+1};
//      single uint B/A loads; interior runs -> float2 store; boundaries -> atomics
#define EPB 320
#define EPW 40
__global__ __launch_bounds__(512) void edge_kernel(
    const ushort* __restrict__ Abuf, const ushort* __restrict__ Bbuf,
    const uint4* __restrict__ epack, const float4* __restrict__ tailpack,
    float* __restrict__ T)
{
    __shared__ __align__(16) uint4 ep_s[EPB];

    int tid = threadIdx.x;
    size_t p0 = (size_t)blockIdx.x * EPB;
    if (tid < EPB) ep_s[tid] = epack[p0 + tid];
    __syncthreads();

    int wid = tid >> 6, lane = tid & 63;
    int base = wid * EPW;
    float4 tp0 = tailpack[2 * lane];
    float4 tp1 = tailpack[2 * lane + 1];

    uint4 p = ep_s[base];
    int prev = (int)p.y;
    uint au = ((const uint*)(Abuf + (size_t)prev * HID))[lane];
    float a0 = bf2f((ushort)(au & 0xffffu));
    float a1 = bf2f((ushort)(au >> 16));
    float acc0 = 0.f, acc1 = 0.f;
    bool first = true;

#pragma unroll 4
    for (int j = 0; j < EPW; ++j) {
        p = ep_s[base + j];
        int d = (int)p.y;
        if (d != prev) {                    // wave-uniform branch
            float* Tr = T + (size_t)prev * HID + 2 * lane;
            if (first) {
                atomicAdd(Tr + 0, acc0);
                atomicAdd(Tr + 1, acc1);
            } else {
                *(float2*)Tr = make_float2(acc0, acc1);   // run interior: exclusive
            }
            first = false;
            acc0 = 0.f; acc1 = 0.f;
            prev = d;
            au = ((const uint*)(Abuf + (size_t)d * HID))[lane];
            a0 = bf2f((ushort)(au & 0xffffu));
            a1 = bf2f((ushort)(au >> 16));
        }
        uint bu = ((const uint*)(Bbuf + (size_t)p.x * HID))[lane];
        float e0 = bf2f((ushort)(p.z & 0xffffu));
        float e1 = bf2f((ushort)(p.z >> 16));
        float e2 = bf2f((ushort)(p.w & 0xffffu));
        float t0 = fmaf(e0, tp0.x, fmaf(e1, tp0.y, fmaf(e2, tp0.z, tp0.w)))
                   + a0 + bf2f((ushort)(bu & 0xffffu));
        float t1 = fmaf(e0, tp1.x, fmaf(e1, tp1.y, fmaf(e2, tp1.z, tp1.w)))
                   + a1 + bf2f((ushort)(bu >> 16));
        acc0 += fmaxf(t0, 0.f);
        acc1 += fmaxf(t1, 0.f);
    }
    float* Tr = T + (size_t)prev * HID + 2 * lane;   // last run: boundary
    atomicAdd(Tr + 0, acc0);
    atomicAdd(Tr + 1, acc1);
}

// ---- upd: aggr = T@W2 + deg*b2; node MLP + residual + MFMA decode.
__global__ __launch_bounds__(512, 6) void upd_kernel(
    const ushort* __restrict__ hb, const float* __restrict__ T,
    const uint* __restrict__ rowptr,
    const ushort* __restrict__ w2t, const float* __restrict__ mb2,
    const float* __restrict__ ub1, const float* __restrict__ ub2,
    const ushort* __restrict__ uw1t, const ushort* __restrict__ uw2t,
    const ushort* __restrict__ dec_wt, const float* __restrict__ dec_b,
    float* __restrict__ out)
{
    __shared__ __align__(16) ushort comb[64][280];   // [h | aggr] -> [hf | aggr]
    __shared__ __align__(16) ushort Tt[64][136];     // T bf16 -> t1, pitch 272B
    __shared__ float deg_s[64];

    int tid = threadIdx.x;
    int n0 = blockIdx.x * 64;

    {
        int el = tid >> 3, q = tid & 7;
        int n = n0 + el;
        if (n < N_NODES) {
            const uint4* gp = (const uint4*)(hb + (size_t)n * HID + q * 16);
            uint4* lp = (uint4*)&comb[el][q * 16];
            lp[0] = gp[0]; lp[1] = gp[1];
            const float4* tpp = (const float4*)(T + (size_t)n * HID + q * 16);
            union { ushort u[16]; uint4 v[2]; } tv;
#pragma unroll
            for (int i = 0; i < 4; ++i) {
                float4 v = tpp[i];
                tv.u[i * 4 + 0] = f2bf(v.x);
                tv.u[i * 4 + 1] = f2bf(v.y);
                tv.u[i * 4 + 2] = f2bf(v.z);
                tv.u[i * 4 + 3] = f2bf(v.w);
            }
            *(uint4*)&Tt[el][q * 16]     = tv.v[0];
            *(uint4*)&Tt[el][q * 16 + 8] = tv.v[1];
        } else {
            uint4 z = make_uint4(0, 0, 0, 0);
            uint4* lp = (uint4*)&comb[el][q * 16];
            lp[0] = z; lp[1] = z;
            *(uint4*)&Tt[el][q * 16]     = z;
            *(uint4*)&Tt[el][q * 16 + 8] = z;
        }
        if (tid < 64) {
            int n2 = n0 + tid;
            deg_s[tid] = (n2 < N_NODES) ? (float)(rowptr[n2 + 1] - rowptr[n2]) : 0.f;
        }
    }
    __syncthreads();

    int lane = tid & 63;
    int wid  = tid >> 6;
    int cg   = wid & 3;
    int mg   = wid >> 2;
    int lhi  = lane >> 4;
    int llo  = lane & 15;
    int col0 = cg * 32 + llo;
    int col1 = cg * 32 + 16 + llo;

    // ---- aggr = Tt @ W2 + deg*b2 -> comb[.,128:256] ----
    {
        floatx4 acc[2][2];
        float b0 = mb2[col0], b1 = mb2[col1];
#pragma unroll
        for (int lm = 0; lm < 2; ++lm)
#pragma unroll
            for (int r = 0; r < 4; ++r) {
                int row = (mg * 2 + lm) * 16 + lhi * 4 + r;
                acc[lm][0][r] = deg_s[row] * b0;
                acc[lm][1][r] = deg_s[row] * b1;
            }
        const ushort* bp0 = w2t + (size_t)col0 * 128 + lhi * 8;
        const ushort* bp1 = w2t + (size_t)col1 * 128 + lhi * 8;
#pragma unroll
        for (int kk = 0; kk < 4; ++kk) {
            short8 bf0 = *(const short8*)(bp0 + kk * 32);
            short8 bf1 = *(const short8*)(bp1 + kk * 32);
#pragma unroll
            for (int lm = 0; lm < 2; ++lm) {
                int row = (mg * 2 + lm) * 16 + llo;
                short8 a = *(const short8*)((const char*)Tt + (size_t)row * 272 + kk * 64 + lhi * 16);
                acc[lm][0] = __builtin_amdgcn_mfma_f32_16x16x32_bf16(a, bf0, acc[lm][0], 0, 0, 0);
                acc[lm][1] = __builtin_amdgcn_mfma_f32_16x16x32_bf16(a, bf1, acc[lm][1], 0, 0, 0);
            }
        }
#pragma unroll
        for (int lm = 0; lm < 2; ++lm)
#pragma unroll
            for (int r = 0; r < 4; ++r) {
                int row = (mg * 2 + lm) * 16 + lhi * 4 + r;
                comb[row][128 + col0] = f2bf(acc[lm][0][r]);
                comb[row][128 + col1] = f2bf(acc[lm][1][r]);
            }
    }
    __syncthreads();

    // ---- layer 1: comb @ uw1 + ub1, relu -> Tt (T data now dead) ----
    {
        floatx4 acc[2][2];
        float b0 = ub1[col0], b1 = ub1[col1];
#pragma unroll
        for (int lm = 0; lm < 2; ++lm)
#pragma unroll
            for (int r = 0; r < 4; ++r) { acc[lm][0][r] = b0; acc[lm][1][r] = b1; }
        const ushort* bp0 = uw1t + (size_t)col0 * 256 + lhi * 8;
        const ushort* bp1 = uw1t + (size_t)col1 * 256 + lhi * 8;
#pragma unroll
        for (int kk = 0; kk < 8; ++kk) {
            short8 bf0 = *(const short8*)(bp0 + kk * 32);
            short8 bf1 = *(const short8*)(bp1 + kk * 32);
#pragma unroll
            for (int lm = 0; lm < 2; ++lm) {
                int row = (mg * 2 + lm) * 16 + llo;
                short8 a = *(const short8*)((const char*)comb + (size_t)row * 560 + kk * 64 + lhi * 16);
                acc[lm][0] = __builtin_amdgcn_mfma_f32_16x16x32_bf16(a, bf0, acc[lm][0], 0, 0, 0);
                acc[lm][1] = __builtin_amdgcn_mfma_f32_16x16x32_bf16(a, bf1, acc[lm][1], 0, 0, 0);
            }
        }
        __syncthreads();
#pragma unroll
        for (int lm = 0; lm < 2; ++lm)
#pragma unroll
            for (int r = 0; r < 4; ++r) {
                int row = (mg * 2 + lm) * 16 + lhi * 4 + r;
                Tt[row][col0] = f2bf(fmaxf(acc[lm][0][r], 0.f));
                Tt[row][col1] = f2bf(fmaxf(acc[lm][1][r], 0.f));
            }
    }
    __syncthreads();

    // ---- layer 2 + residual -> comb[.,0:128] (hf over h, same-thread elements) -
    {
        floatx4 acc[2][2];
        float b0 = ub2[col0], b1 = ub2[col1];
#pragma unroll
        for (int lm = 0; lm < 2; ++lm)
#pragma unroll
            for (int r = 0; r < 4; ++r) { acc[lm][0][r] = b0; acc[lm][1][r] = b1; }
        const ushort* bp0 = uw2t + (size_t)col0 * 128 + lhi * 8;
        const ushort* bp1 = uw2t + (size_t)col1 * 128 + lhi * 8;
#pragma unroll
        for (int kk = 0; kk < 4; ++kk) {
            short8 bf0 = *(const short8*)(bp0 + kk * 32);
            short8 bf1 = *(const short8*)(bp1 + kk * 32);
#pragma unroll
            for (int lm = 0; lm < 2; ++lm) {
                int row = (mg * 2 + lm) * 16 + llo;
                short8 a = *(const short8*)((const char*)Tt + (size_t)row * 272 + kk * 64 + lhi * 16);
                acc[lm][0] = __builtin_amdgcn_mfma_f32_16x16x32_bf16(a, bf0, acc[lm][0], 0, 0, 0);
                acc[lm][1] = __builtin_amdgcn_mfma_f32_16x16x32_bf16(a, bf1, acc[lm][1], 0, 0, 0);
            }
        }
#pragma unroll
        for (int lm = 0; lm < 2; ++lm)
#pragma unroll
            for (int r = 0; r < 4; ++r) {
                int row = (mg * 2 + lm) * 16 + lhi * 4 + r;
                float h0 = bf2f(comb[row][col0]);
                float h1 = bf2f(comb[row][col1]);
                comb[row][col0] = f2bf(h0 + acc[lm][0][r]);
                comb[row][col1] = f2bf(h1 + acc[lm][1][r]);
            }
    }
    __syncthreads();

    // ---- decode via MFMA: [64,128] @ [128,16(pad)] ; waves 0-3, 4 MFMA each ----
    if (wid < 4) {
        floatx4 accd;
        float db = (llo < 5) ? dec_b[llo] : 0.f;
#pragma unroll
        for (int r = 0; r < 4; ++r) accd[r] = db;
        const ushort* bp = dec_wt + (size_t)llo * 128 + lhi * 8;
#pragma unroll
        for (int kk = 0; kk < 4; ++kk) {
            short8 bf = *(const short8*)(bp + kk * 32);
            int row = wid * 16 + llo;
            short8 a = *(const short8*)((const char*)comb + (size_t)row * 560 + kk * 64 + lhi * 16);
            accd = __builtin_amdgcn_mfma_f32_16x16x32_bf16(a, bf, accd, 0, 0, 0);
        }
        if (llo < 5) {
#pragma unroll
            for (int r = 0; r < 4; ++r) {
                int n = n0 + wid * 16 + lhi * 4 + r;
                if (n < N_NODES) out[(size_t)n * 5 + llo] = accd[r];
            }
        }
    }
}

extern "C" void kernel_launch(void* const* d_in, const int* in_sizes, int n_in,
                              void* d_out, int out_size, void* d_ws, size_t ws_size,
                              hipStream_t stream) {
    const float* x     = (const float*)d_in[0];
    const int*   ei    = (const int*)d_in[1];
    const float* ea    = (const float*)d_in[2];
    const float* enc_w = (const float*)d_in[3];
    const float* enc_b = (const float*)d_in[4];
    const float* dec_w = (const float*)d_in[5];
    const float* dec_b = (const float*)d_in[6];
    // Only layer l=3 contributes (loop overwrites h_update; h never changes).
    const float* mw1 = (const float*)d_in[7]  + (size_t)3 * 259 * HID;
    const float* mb1 = (const float*)d_in[8]  + (size_t)3 * HID;
    const float* mw2 = (const float*)d_in[9]  + (size_t)3 * HID * HID;
    const float* mb2 = (const float*)d_in[10] + (size_t)3 * HID;
    const float* uw1 = (const float*)d_in[11] + (size_t)3 * 256 * HID;
    const float* ub1 = (const float*)d_in[12] + (size_t)3 * HID;
    const float* uw2 = (const float*)d_in[13] + (size_t)3 * HID * HID;
    const float* ub2 = (const float*)d_in[14] + (size_t)3 * HID;

    char* w = (char*)d_ws;
    ushort* hb     = (ushort*)w;  w += (size_t)N_NODES * HID * 2;   // 12.8MB
    ushort* Abuf   = (ushort*)w;  w += (size_t)N_NODES * HID * 2;   // 12.8MB
    ushort* Bbuf   = (ushort*)w;  w += (size_t)N_NODES * HID * 2;   // 12.8MB
    float*  T      = (float*)w;   w += (size_t)N_NODES * HID * 4;   // 25.6MB
    uint*   counts = (uint*)w;    w += (size_t)50016 * 4;
    uint*   cursor = (uint*)w;    w += (size_t)50016 * 4;
    uint*   rowptr = (uint*)w;    w += (size_t)50016 * 4;
    uint*   partials=(uint*)w;    w += (size_t)256 * 4;
    uint4*  epack  = (uint4*)w;   w += (size_t)N_EDGES * 16;        // 12.8MB
    ushort* w1at   = (ushort*)w;  w += (size_t)128 * 128 * 2;
    ushort* w1bt   = (ushort*)w;  w += (size_t)128 * 128 * 2;
    ushort* w2t    = (ushort*)w;  w += (size_t)128 * 128 * 2;
    ushort* uw1t   = (ushort*)w;  w += (size_t)128 * 256 * 2;
    ushort* uw2t   = (ushort*)w;  w += (size_t)128 * 128 * 2;
    ushort* dec_wt = (ushort*)w;  w += (size_t)16 * 128 * 2;
    float4* tailpack = (float4*)w; w += (size_t)128 * 16;
    float*  out    = (float*)d_out;

    prep_kernel<<<(1725488 + 255) / 256, 256, 0, stream>>>(
        mw1, mb1, mw2, uw1, uw2, dec_w, w1at, w1bt, w2t, uw1t, uw2t, dec_wt,
        tailpack, (float4*)counts, (float4*)cursor, (float4*)T);
    hist_kernel<<<(N_EDGES + 255) / 256, 256, 0, stream>>>(ei, counts);
    scan1_kernel<<<SCAN_B, 256, 0, stream>>>(counts, partials);
    scan3_kernel<<<SCAN_B, 256, 0, stream>>>(counts, partials, rowptr);
    build_kernel<<<(N_EDGES + 255) / 256, 256, 0, stream>>>(ei, ea, rowptr, cursor, epack);
    pre_kernel<<<(N_NODES + 63) / 64, 512, 0, stream>>>(
        x, enc_w, enc_b, w1at, w1bt, hb, Abuf, Bbuf);
    edge_kernel<<<N_EDGES / EPB, 512, 0, stream>>>(Abuf, Bbuf, epack, tailpack, T);
    upd_kernel<<<(N_NODES + 63) / 64, 512, 0, stream>>>(
        hb, T, rowptr, w2t, mb2, ub1, ub2, uw1t, uw2t, dec_wt, dec_b, out);
}